// Round 12
// baseline (162.823 us; speedup 1.0000x reference)
//
#include <hip/hip_runtime.h>
#include <hip/hip_bf16.h>
#include <math.h>

#define V_N   6890
#define N_PTS 16384
#define D_IN  700
#define D_INP 704      // padded K for layer 1
#define D_HID 256
#define D_OUT 283
#define NCHUNK 32
#define CHUNK  216     // ceil(6890/32)
#define GAP_EPS 1e-4f  // combined fp32 error (ours + reference) ~1e-5 -> 10x margin

// ws layout (float units; all offsets *4 bytes, 16B aligned)
#define RINV4_OFF 0             // V*12 -> 82688 (padded 3x float4 rows)
#define KP4_OFF   82688         // V*4 -> 27584
#define RP4_OFF   110272        // V*4 -> 27584
#define PB4_OFF   170640        // N*NCHUNK float4 (point-major)
#define WT1_OFF   2267792       // 90112
#define WT2_OFF   2357904       // 32768
#define WT3_OFF   2390672       // 32768
#define X_OFF     2423440       // 5767168

typedef __attribute__((ext_vector_type(8))) short short8;
typedef __attribute__((ext_vector_type(4))) float f32x4;

__device__ __forceinline__ unsigned short f2bf(float f) {
    unsigned int u = __builtin_bit_cast(unsigned int, f);
    u += 0x7fffu + ((u >> 16) & 1u);   // RNE
    return (unsigned short)(u >> 16);
}

// HW transcendental: sin(x) = v_sin_f32(fract(x/2pi)) -- 3 VALU ops vs ~100 libm.
__device__ __forceinline__ float fsin(float x) {
    return __builtin_amdgcn_sinf(__builtin_amdgcn_fractf(x * 0.15915494309189535f));
}
__device__ __forceinline__ float fcos(float x) {
    return __builtin_amdgcn_cosf(__builtin_amdgcn_fractf(x * 0.15915494309189535f));
}

__device__ __forceinline__ void glds16(const void* g, void* l) {
    __builtin_amdgcn_global_load_lds(
        (const __attribute__((address_space(1))) void*)g,
        (__attribute__((address_space(3))) void*)l, 16, 0, 0);
}

// XOR-swizzle for [R][32]bf16 LDS tiles read as 16-row x 16B-group fragments.
__device__ __forceinline__ int swzoff(int r, int sub) {
    return ((r << 2) | (sub ^ ((r >> 1) & 3))) << 4;   // byte offset
}

// whole-wave fp64 exact rescan of point nn; 4-way batched independent loads.
__device__ __forceinline__ int rescan64(const float* __restrict__ pts,
                                        const float4* __restrict__ kp4,
                                        int nn, int lane) {
    double pxd = (double)pts[nn*6+0], pyd = (double)pts[nn*6+1], pzd = (double)pts[nn*6+2];
    double ppd = pxd*pxd + pyd*pyd + pzd*pzd;
    double best = 1e300; int bbi = 0x7fffffff;
    for (int b = lane; b < 6912; b += 256) {
        int j0 = b, j1 = b + 64, j2 = b + 128, j3 = b + 192;
        float4 k0 = kp4[min(j0, V_N-1)];
        float4 k1 = kp4[min(j1, V_N-1)];
        float4 k2 = kp4[min(j2, V_N-1)];
        float4 k3 = kp4[min(j3, V_N-1)];
#define EVAL(kk, jj)                                                          \
        if (jj < V_N) {                                                       \
            double kx = (double)kk.x, ky = (double)kk.y, kz = (double)kk.z;   \
            double d = ppd - 2.0*(pxd*kx + pyd*ky + pzd*kz)                   \
                     + (kx*kx + ky*ky + kz*kz);                               \
            if (d < best || (d == best && jj < bbi)) { best = d; bbi = jj; }  \
        }
        EVAL(k0, j0); EVAL(k1, j1); EVAL(k2, j2); EVAL(k3, j3);
#undef EVAL
    }
#pragma unroll
    for (int off = 32; off >= 1; off >>= 1) {
        double od = __shfl_xor(best, off);
        int    oi = __shfl_xor(bbi, off);
        if (od < best || (od == best && oi < bbi)) { best = od; bbi = oi; }
    }
    return bbi;
}

// ---------------- merged: KNN scan (blocks 0..511, 4 pts/thread) + prep + wconv
#define SCAN_BLOCKS 512
#define PREP_BLOCKS 27
__global__ __launch_bounds__(256) void prep_scan_kernel(
    const float* __restrict__ pts, const float* __restrict__ keyp,
    const float* __restrict__ trans, const float* __restrict__ restp,
    const float* __restrict__ W1, const float* __restrict__ W2,
    const float* __restrict__ W3,
    float4* __restrict__ rinv4, float4* __restrict__ kp4, float4* __restrict__ rp4,
    unsigned short* __restrict__ wt1, unsigned short* __restrict__ wt2,
    unsigned short* __restrict__ wt3, float4* __restrict__ pb4)
{
    __shared__ float4 s_kp[CHUNK];   // 3.4 KB, scan blocks only
    int bx = blockIdx.x, tid = threadIdx.x;

    if (bx < SCAN_BLOCKS) {
        int g = bx & 15;             // point-group (1024 points)
        int c = bx >> 4;             // chunk
        int nA = g * 1024 + tid;
        int nB = nA + 256, nC = nA + 512, nD = nA + 768;
        int v0 = c * CHUNK;
        int nv = min(V_N - v0, CHUNK);
        if (tid < nv) {
            int v = v0 + tid;
            float kx = keyp[v*3+0], ky = keyp[v*3+1], kz = keyp[v*3+2];
            s_kp[tid] = make_float4(kx, ky, kz, kx*kx + ky*ky + kz*kz);
        }
        __syncthreads();

        float pxA = -2.0f*pts[nA*6+0], pyA = -2.0f*pts[nA*6+1], pzA = -2.0f*pts[nA*6+2];
        float pxB = -2.0f*pts[nB*6+0], pyB = -2.0f*pts[nB*6+1], pzB = -2.0f*pts[nB*6+2];
        float pxC = -2.0f*pts[nC*6+0], pyC = -2.0f*pts[nC*6+1], pzC = -2.0f*pts[nC*6+2];
        float pxD = -2.0f*pts[nD*6+0], pyD = -2.0f*pts[nD*6+1], pzD = -2.0f*pts[nD*6+2];
        float m1A = 1e30f, m2A = 1e30f; int biA = 0x7fffffff;
        float m1B = 1e30f, m2B = 1e30f; int biB = 0x7fffffff;
        float m1C = 1e30f, m2C = 1e30f; int biC = 0x7fffffff;
        float m1D = 1e30f, m2D = 1e30f; int biD = 0x7fffffff;

#define KP1(P, kk, jj)                                                      \
    {                                                                       \
        float d = __builtin_fmaf(px##P, kk.x,                               \
                  __builtin_fmaf(py##P, kk.y,                               \
                  __builtin_fmaf(pz##P, kk.z, kk.w)));                      \
        bool lt = d < m1##P;                                                \
        bi##P = lt ? (jj) : bi##P;                                          \
        m2##P = __builtin_amdgcn_fmed3f(m1##P, m2##P, d);                   \
        m1##P = fminf(m1##P, d);                                            \
    }
#define KNN_STEP(kk, jj)                                                    \
    { KP1(A, kk, jj) KP1(B, kk, jj) KP1(C, kk, jj) KP1(D, kk, jj) }

        int j = 0;
        for (; j + 8 <= nv; j += 8) {
            float4 k0 = s_kp[j],   k1 = s_kp[j+1], k2 = s_kp[j+2], k3 = s_kp[j+3];
            float4 k4 = s_kp[j+4], k5 = s_kp[j+5], k6 = s_kp[j+6], k7 = s_kp[j+7];
            KNN_STEP(k0, v0+j);   KNN_STEP(k1, v0+j+1);
            KNN_STEP(k2, v0+j+2); KNN_STEP(k3, v0+j+3);
            KNN_STEP(k4, v0+j+4); KNN_STEP(k5, v0+j+5);
            KNN_STEP(k6, v0+j+6); KNN_STEP(k7, v0+j+7);
        }
        for (; j < nv; ++j) {
            float4 k0 = s_kp[j];
            KNN_STEP(k0, v0+j);
        }
#undef KNN_STEP
#undef KP1
        pb4[(size_t)nA * NCHUNK + c] = make_float4(m1A, m2A, __int_as_float(biA), 0.0f);
        pb4[(size_t)nB * NCHUNK + c] = make_float4(m1B, m2B, __int_as_float(biB), 0.0f);
        pb4[(size_t)nC * NCHUNK + c] = make_float4(m1C, m2C, __int_as_float(biC), 0.0f);
        pb4[(size_t)nD * NCHUNK + c] = make_float4(m1D, m2D, __int_as_float(biD), 0.0f);

    } else if (bx < SCAN_BLOCKS + PREP_BLOCKS) {
        int v = (bx - SCAN_BLOCKS) * 256 + tid;
        if (v >= V_N) return;
        float m[16];
#pragma unroll
        for (int i = 0; i < 16; ++i) m[i] = trans[i * V_N + v];

        float i0  =  m[5]*m[10]*m[15] - m[5]*m[11]*m[14] - m[9]*m[6]*m[15] + m[9]*m[7]*m[14] + m[13]*m[6]*m[11] - m[13]*m[7]*m[10];
        float i4  = -m[4]*m[10]*m[15] + m[4]*m[11]*m[14] + m[8]*m[6]*m[15] - m[8]*m[7]*m[14] - m[12]*m[6]*m[11] + m[12]*m[7]*m[10];
        float i8  =  m[4]*m[9]*m[15]  - m[4]*m[11]*m[13] - m[8]*m[5]*m[15] + m[8]*m[7]*m[13] + m[12]*m[5]*m[11] - m[12]*m[7]*m[9];
        float i12 = -m[4]*m[9]*m[14]  + m[4]*m[10]*m[13] + m[8]*m[5]*m[14] - m[8]*m[6]*m[13] - m[12]*m[5]*m[10] + m[12]*m[6]*m[9];
        float i1  = -m[1]*m[10]*m[15] + m[1]*m[11]*m[14] + m[9]*m[2]*m[15] - m[9]*m[3]*m[14] - m[13]*m[2]*m[11] + m[13]*m[3]*m[10];
        float i5  =  m[0]*m[10]*m[15] - m[0]*m[11]*m[14] - m[8]*m[2]*m[15] + m[8]*m[3]*m[14] + m[12]*m[2]*m[11] - m[12]*m[3]*m[10];
        float i9  = -m[0]*m[9]*m[15]  + m[0]*m[11]*m[13] + m[8]*m[1]*m[15] - m[8]*m[3]*m[13] - m[12]*m[1]*m[11] + m[12]*m[3]*m[9];
        float i2  =  m[1]*m[6]*m[15]  - m[1]*m[7]*m[14]  - m[5]*m[2]*m[15] + m[5]*m[3]*m[14] + m[13]*m[2]*m[7]  - m[13]*m[3]*m[6];
        float i6  = -m[0]*m[6]*m[15]  + m[0]*m[7]*m[14]  + m[4]*m[2]*m[15] - m[4]*m[3]*m[14] - m[12]*m[2]*m[7]  + m[12]*m[3]*m[6];
        float i10 =  m[0]*m[5]*m[15]  - m[0]*m[7]*m[13]  - m[4]*m[1]*m[15] + m[4]*m[3]*m[13] + m[12]*m[1]*m[7]  - m[12]*m[3]*m[5];

        float det = m[0]*i0 + m[1]*i4 + m[2]*i8 + m[3]*i12;
        float id = 1.0f / det;
        rinv4[v*3+0] = make_float4(i0*id, i1*id, i2*id, i4*id);
        rinv4[v*3+1] = make_float4(i5*id, i6*id, i8*id, i9*id);
        rinv4[v*3+2] = make_float4(i10*id, 0.0f, 0.0f, 0.0f);

        float kx = keyp[v*3], ky = keyp[v*3+1], kz = keyp[v*3+2];
        kp4[v] = make_float4(kx, ky, kz, kx*kx + ky*ky + kz*kz);
        rp4[v] = make_float4(restp[v*3], restp[v*3+1], restp[v*3+2], 0.0f);
    } else {
        int idx = (bx - SCAN_BLOCKS - PREP_BLOCKS) * 256 + tid;
        const int N1 = 256 * D_INP;
        const int N2 = 256 * 256;
        if (idx < N1) {
            int n = idx / D_INP, k = idx - n * D_INP;
            float v = (k < D_IN) ? W1[k * 256 + n] : 0.0f;
            wt1[n * D_INP + k] = f2bf(v);
        } else if (idx < N1 + N2) {
            int t = idx - N1;
            int n = t >> 8, k = t & 255;
            wt2[n * 256 + k] = f2bf(W2[k * 256 + n]);
        } else if (idx < N1 + 2 * N2) {
            int t = idx - N1 - N2;
            int n = t >> 8, k = t & 255;
            wt3[n * 256 + k] = f2bf(W3[k * 256 + n]);
        }
    }
}

// ---------------- features v11: 1 point/wave (halved serial chain) ----------
// R11 insight: feat is latency-structured at full static occupancy (32
// waves/CU) -- more blocks can't raise residency, but halving the per-wave
// serial chain (Phase B once, not twice; <=1 rescan/wave instead of <=2)
// shortens both the pipeline depth and the straggler-tail quantum. 4096
// blocks keep CUs saturated in two back-to-back rounds. Same merge math,
// same certification, same rescan policy -> bit-identical output.
__global__ __launch_bounds__(256) void feat_kernel(
    const float* __restrict__ pts, const int* __restrict__ neigh,
    const float* __restrict__ latent, const float4* __restrict__ rinv4,
    const float4* __restrict__ kp4, const float4* __restrict__ rp4,
    const float4* __restrict__ pb4, unsigned short* __restrict__ X,
    float* __restrict__ out)
{
    __shared__ float s_vf[4][29];   // [wave][28+pad]
    __shared__ float s_dir[4][4];

    int t = threadIdx.x;
    int w = t >> 6, lane = t & 63;
    int n = blockIdx.x * 4 + w;        // this wave's point
    int g = lane & 31;

    // hoisted pts load (independent of pb4 merge)
    float px = pts[n*6+0], py = pts[n*6+1], pz = pts[n*6+2];

    // ---- Phase R: coalesced load (both halves read same 512B) + merge ----
    float4 P = pb4[(size_t)n * NCHUNK + g];
    float m1 = P.x, m2 = P.y;
    int   bi = __float_as_int(P.z);
#pragma unroll
    for (int off = 1; off <= 16; off <<= 1) {     // xor within each half
        float o1 = __shfl_xor(m1, off);
        float o2 = __shfl_xor(m2, off);
        int   ob = __shfl_xor(bi, off);
        float nm2 = fminf(fminf(m2, o2), fmaxf(m1, o1));
        bool take = (o1 < m1) || (o1 == m1 && ob < bi);
        bi = take ? ob : bi;
        m1 = fminf(m1, o1);
        m2 = nm2;
    }
    // all lanes now hold the full 32-chunk lex-min; wave-uniform flag
    if (m2 - m1 < GAP_EPS) bi = rescan64(pts, kp4, n, lane);

    // ---- Phase A: gathers (lanes 0..7) ----
    int k8 = bi;                                   // wave-uniform
    int v7 = 0;
    if (lane < 7) {
        v7 = neigh[k8*7 + lane];
        float4 kq = kp4[v7];
        float4 rq = rp4[v7];
        float dx = px - kq.x, dy = py - kq.y, dz = pz - kq.z;
        s_vf[w][lane*3+0] = rq.x;
        s_vf[w][lane*3+1] = rq.y;
        s_vf[w][lane*3+2] = rq.z;
        s_vf[w][21+lane]  = sqrtf(dx*dx + dy*dy + dz*dz);
    } else if (lane == 7) {
        float4 kq = kp4[k8];
        float ddx = px - kq.x, ddy = py - kq.y, ddz = pz - kq.z;
        float4 R0 = rinv4[k8*3+0];
        float4 R1 = rinv4[k8*3+1];
        float4 R2 = rinv4[k8*3+2];
        float d0 = R0.x*ddx + R0.y*ddy + R0.z*ddz;
        float d1 = R0.w*ddx + R1.x*ddy + R1.y*ddz;
        float d2 = R1.z*ddx + R1.w*ddy + R2.x*ddz;
        float nrm = fmaxf(sqrtf(d0*d0 + d1*d1 + d2*d2), 1e-12f);
        s_dir[w][0] = d0/nrm; s_dir[w][1] = d1/nrm; s_dir[w][2] = d2/nrm;
    }
    // no barrier: wave reads only its own LDS rows (intra-wave lgkmcnt)

    // ---- Phase B: posenc + stores (single point) ----
    float dir0 = s_dir[w][0];                      // LDS broadcasts
    float dir1 = s_dir[w][1];
    float dir2 = s_dir[w][2];

    // output tail (fp32): [dir(3), sin f-major (12), cos (12)]
    if (lane < 27) {
        float val;
        if (lane < 3) {
            val = (lane == 0) ? dir0 : (lane == 1) ? dir1 : dir2;
        } else {
            int tt = (lane < 15) ? lane - 3 : lane - 15;
            int m = tt % 3;
            float db = (m == 0) ? dir0 : (m == 1) ? dir1 : dir2;
            float a = db * (float)(1 << (tt/3));
            val = (lane < 15) ? fsin(a) : fcos(a);
        }
        out[(size_t)n*D_OUT + 256 + lane] = val;
    }

    // X row bf16, quad-per-lane; vf from wave-private LDS
#pragma unroll
    for (int it = 0; it < 3; ++it) {
        int base = it * 256 + (lane << 2);
        bool in_range = base < D_INP;
        int region = (base < 28) ? 0 : (base < 308) ? 1 : (base < 588) ? 2
                   : (base < 700) ? 3 : 4;

        int t0 = (region == 1) ? base - 28 : (region == 2) ? base - 308 : 0;
        int q = t0 / 28;
        int r = t0 - q * 28;
        float f0 = (float)(1 << q);
        float a[4];
#pragma unroll
        for (int jj = 0; jj < 4; ++jj) {
            int rj; float fj;
            if (region == 0) { rj = base + jj; fj = 1.0f; }
            else if (region <= 2) {
                rj = r + jj; fj = f0;
                if (rj >= 28) { rj -= 28; fj = f0 * 2.0f; }
            } else { rj = 0; fj = 0.0f; }
            a[jj] = s_vf[w][rj] * fj;       // ds_read_b32
        }
        // latent neighbor index via full-exec shuffle (v7 valid at lanes 0..6)
        int idxc = (region == 3) ? (base - 588) >> 4 : 0;
        int vL = __shfl(v7, idxc);

        unsigned short r0, r1, r2, r3;
        if (region == 0) {
            r0 = f2bf(a[0]); r1 = f2bf(a[1]); r2 = f2bf(a[2]); r3 = f2bf(a[3]);
        } else if (region == 1) {
            r0 = f2bf(fsin(a[0])); r1 = f2bf(fsin(a[1]));
            r2 = f2bf(fsin(a[2])); r3 = f2bf(fsin(a[3]));
        } else if (region == 2) {
            r0 = f2bf(fcos(a[0])); r1 = f2bf(fcos(a[1]));
            r2 = f2bf(fcos(a[2])); r3 = f2bf(fcos(a[3]));
        } else if (region == 3) {
            int t3 = base - 588;
            float4 lv = *(const float4*)&latent[vL * 16 + (t3 & 15)];
            r0 = f2bf(lv.x); r1 = f2bf(lv.y); r2 = f2bf(lv.z); r3 = f2bf(lv.w);
        } else {
            r0 = r1 = r2 = r3 = 0;
        }
        if (in_range)
            *(ushort4*)&X[(size_t)n * D_INP + base] = make_ushort4(r0, r1, r2, r3);
    }
}

// ---------------- fused 3-layer MLP: 32 rows/block, 2 blocks/CU --------------
#define HLD 264
__global__ __launch_bounds__(512) void mlp_kernel(
    const unsigned short* __restrict__ X,
    const unsigned short* __restrict__ wt1,
    const unsigned short* __restrict__ wt2,
    const unsigned short* __restrict__ wt3,
    const float* __restrict__ b1, const float* __restrict__ b2,
    const float* __restrict__ b3, float* __restrict__ out)
{
    __shared__ unsigned short As[2][32 * 32];     // 4 KB  (swizzled slots)
    __shared__ unsigned short Ws[2][256 * 32];    // 32 KB (swizzled slots)
    __shared__ unsigned short H1[32 * HLD];       // 16.9 KB
    __shared__ unsigned short H2[32 * HLD];       // 16.9 KB

    int t = threadIdx.x, l = t & 63, w = t >> 6;
    int bm = blockIdx.x * 32;
    int nbase = w * 32;
    int lrow = l & 15, lk = (l >> 4) * 8, sub = l >> 4;
    int col0 = l & 15, rquad = (l >> 4) * 4;

    f32x4 acc[2][2];
    short8 af[2], bf[2];

    auto stageA = [&](int buf, int k0) {
        if (t < 128) {
            int r = t >> 2, sg = (t & 3) ^ ((r >> 1) & 3);
            glds16(X + (size_t)(bm + r) * D_INP + k0 + sg * 8,
                   (char*)As[buf] + t * 16);
        }
    };
    auto stageW = [&](int buf, const unsigned short* wsrc, int ld, int k0) {
#pragma unroll
        for (int i = 0; i < 2; ++i) {
            int c = i * 512 + t;
            int r = c >> 2, sg = (c & 3) ^ ((r >> 1) & 3);
            glds16(wsrc + (size_t)r * ld + k0 + sg * 8,
                   (char*)Ws[buf] + (size_t)c * 16);
        }
    };

    // ---- layer 1: X[704] @ wt1^T -> relu -> H1 ----
#pragma unroll
    for (int mi = 0; mi < 2; ++mi)
#pragma unroll
        for (int ni = 0; ni < 2; ++ni) acc[mi][ni] = {0.f, 0.f, 0.f, 0.f};

    stageA(0, 0);
    stageW(0, wt1, D_INP, 0);
    __syncthreads();
    const int NK1 = D_INP / 32;                      // 22
    for (int ks = 0; ks < NK1; ++ks) {
        int cur = ks & 1;
        if (ks + 1 < NK1) {
            stageA(cur ^ 1, (ks + 1) * 32);
            stageW(cur ^ 1, wt1, D_INP, (ks + 1) * 32);
        }
#pragma unroll
        for (int mi = 0; mi < 2; ++mi)
            af[mi] = *(const short8*)((const char*)As[cur] + swzoff(mi*16 + lrow, sub));
#pragma unroll
        for (int ni = 0; ni < 2; ++ni)
            bf[ni] = *(const short8*)((const char*)Ws[cur] + swzoff(nbase + ni*16 + lrow, sub));
#pragma unroll
        for (int mi = 0; mi < 2; ++mi)
#pragma unroll
            for (int ni = 0; ni < 2; ++ni)
                acc[mi][ni] = __builtin_amdgcn_mfma_f32_16x16x32_bf16(
                    af[mi], bf[ni], acc[mi][ni], 0, 0, 0);
        __syncthreads();
    }
    stageW(0, wt2, D_HID, 0);   // prefetch layer-2 under epilogue
#pragma unroll
    for (int mi = 0; mi < 2; ++mi)
#pragma unroll
        for (int ni = 0; ni < 2; ++ni) {
            int col = nbase + ni * 16 + col0;
            float bv = b1[col];
#pragma unroll
            for (int r = 0; r < 4; ++r) {
                int row = mi * 16 + rquad + r;
                H1[row * HLD + col] = f2bf(fmaxf(acc[mi][ni][r] + bv, 0.0f));
            }
        }
    __syncthreads();

    // ---- layer 2: H1 @ wt2^T -> relu -> H2 ----
#pragma unroll
    for (int mi = 0; mi < 2; ++mi)
#pragma unroll
        for (int ni = 0; ni < 2; ++ni) acc[mi][ni] = {0.f, 0.f, 0.f, 0.f};

    const int NK2 = D_HID / 32;                      // 8
    for (int ks = 0; ks < NK2; ++ks) {
        int cur = ks & 1;
        if (ks + 1 < NK2) stageW(cur ^ 1, wt2, D_HID, (ks + 1) * 32);
#pragma unroll
        for (int mi = 0; mi < 2; ++mi)
            af[mi] = *(const short8*)&H1[(mi * 16 + lrow) * HLD + ks * 32 + lk];
#pragma unroll
        for (int ni = 0; ni < 2; ++ni)
            bf[ni] = *(const short8*)((const char*)Ws[cur] + swzoff(nbase + ni*16 + lrow, sub));
#pragma unroll
        for (int mi = 0; mi < 2; ++mi)
#pragma unroll
            for (int ni = 0; ni < 2; ++ni)
                acc[mi][ni] = __builtin_amdgcn_mfma_f32_16x16x32_bf16(
                    af[mi], bf[ni], acc[mi][ni], 0, 0, 0);
        __syncthreads();
    }
    stageW(0, wt3, D_HID, 0);   // prefetch layer-3 under epilogue
#pragma unroll
    for (int mi = 0; mi < 2; ++mi)
#pragma unroll
        for (int ni = 0; ni < 2; ++ni) {
            int col = nbase + ni * 16 + col0;
            float bv = b2[col];
#pragma unroll
            for (int r = 0; r < 4; ++r) {
                int row = mi * 16 + rquad + r;
                H2[row * HLD + col] = f2bf(fmaxf(acc[mi][ni][r] + bv, 0.0f));
            }
        }
    __syncthreads();

    // ---- layer 3: H2 @ wt3^T + b3 -> out (fp32) ----
#pragma unroll
    for (int mi = 0; mi < 2; ++mi)
#pragma unroll
        for (int ni = 0; ni < 2; ++ni) acc[mi][ni] = {0.f, 0.f, 0.f, 0.f};

    for (int ks = 0; ks < NK2; ++ks) {
        int cur = ks & 1;
        if (ks + 1 < NK2) stageW(cur ^ 1, wt3, D_HID, (ks + 1) * 32);
#pragma unroll
        for (int mi = 0; mi < 2; ++mi)
            af[mi] = *(const short8*)&H2[(mi * 16 + lrow) * HLD + ks * 32 + lk];
#pragma unroll
        for (int ni = 0; ni < 2; ++ni)
            bf[ni] = *(const short8*)((const char*)Ws[cur] + swzoff(nbase + ni*16 + lrow, sub));
#pragma unroll
        for (int mi = 0; mi < 2; ++mi)
#pragma unroll
            for (int ni = 0; ni < 2; ++ni)
                acc[mi][ni] = __builtin_amdgcn_mfma_f32_16x16x32_bf16(
                    af[mi], bf[ni], acc[mi][ni], 0, 0, 0);
        __syncthreads();
    }
#pragma unroll
    for (int mi = 0; mi < 2; ++mi)
#pragma unroll
        for (int ni = 0; ni < 2; ++ni) {
            int col = nbase + ni * 16 + col0;
            float bv = b3[col];
#pragma unroll
            for (int r = 0; r < 4; ++r) {
                int row = bm + mi * 16 + rquad + r;
                out[(size_t)row * D_OUT + col] = acc[mi][ni][r] + bv;
            }
        }
}

extern "C" void kernel_launch(void* const* d_in, const int* in_sizes, int n_in,
                              void* d_out, int out_size, void* d_ws, size_t ws_size,
                              hipStream_t stream) {
    const float* pts    = (const float*)d_in[0];
    const float* keyp   = (const float*)d_in[1];
    const float* trans  = (const float*)d_in[2];
    const int*   neigh  = (const int*)d_in[3];
    const float* restp  = (const float*)d_in[4];
    const float* latent = (const float*)d_in[5];
    const float* W1     = (const float*)d_in[6];
    const float* b1     = (const float*)d_in[7];
    const float* W2     = (const float*)d_in[8];
    const float* b2     = (const float*)d_in[9];
    const float* W3     = (const float*)d_in[10];
    const float* b3     = (const float*)d_in[11];
    float* out = (float*)d_out;

    float* wsf = (float*)d_ws;
    float4*         rinv4 = (float4*)(wsf + RINV4_OFF);
    float4*         kp4   = (float4*)(wsf + KP4_OFF);
    float4*         rp4   = (float4*)(wsf + RP4_OFF);
    float4*         pb4   = (float4*)(wsf + PB4_OFF);
    unsigned short* wt1   = (unsigned short*)(wsf + WT1_OFF);
    unsigned short* wt2   = (unsigned short*)(wsf + WT2_OFF);
    unsigned short* wt3   = (unsigned short*)(wsf + WT3_OFF);
    unsigned short* X     = (unsigned short*)(wsf + X_OFF);

    int wconv_blocks = (256*D_INP + 2*256*256 + 255) / 256;
    prep_scan_kernel<<<SCAN_BLOCKS + PREP_BLOCKS + wconv_blocks, 256, 0, stream>>>(
        pts, keyp, trans, restp, W1, W2, W3, rinv4, kp4, rp4, wt1, wt2, wt3, pb4);
    feat_kernel<<<N_PTS/4, 256, 0, stream>>>(pts, neigh, latent, rinv4,
                                             kp4, rp4, pb4, X, out);
    mlp_kernel<<<N_PTS/32, 512, 0, stream>>>(X, wt1, wt2, wt3, b1, b2, b3, out);
}

// Round 13
// 160.298 us; speedup vs baseline: 1.0158x; 1.0158x over previous
//
#include <hip/hip_runtime.h>
#include <hip/hip_bf16.h>
#include <math.h>

#define V_N   6890
#define N_PTS 16384
#define D_IN  700
#define D_INP 704      // padded K for layer 1
#define D_HID 256
#define D_OUT 283
#define NCHUNK 32
#define CHUNK  216     // ceil(6890/32)
#define GAP_EPS 1e-4f  // combined fp32 error (ours + reference) ~1e-5 -> 10x margin

// ws layout (float units; all offsets *4 bytes, 16B aligned)
#define RINV4_OFF 0             // V*12 -> 82688 (padded 3x float4 rows)
#define KP4_OFF   82688         // V*4 -> 27584
#define RP4_OFF   110272        // V*4 -> 27584
#define PB4_OFF   170640        // N*NCHUNK float4 (point-major)
#define WT1_OFF   2267792       // 90112
#define WT2_OFF   2357904       // 32768
#define WT3_OFF   2390672       // 32768
#define X_OFF     2423440       // 5767168

typedef __attribute__((ext_vector_type(8))) short short8;
typedef __attribute__((ext_vector_type(4))) float f32x4;

__device__ __forceinline__ unsigned short f2bf(float f) {
    unsigned int u = __builtin_bit_cast(unsigned int, f);
    u += 0x7fffu + ((u >> 16) & 1u);   // RNE
    return (unsigned short)(u >> 16);
}

// HW transcendental: sin(x) = v_sin_f32(fract(x/2pi)) -- 3 VALU ops vs ~100 libm.
__device__ __forceinline__ float fsin(float x) {
    return __builtin_amdgcn_sinf(__builtin_amdgcn_fractf(x * 0.15915494309189535f));
}
__device__ __forceinline__ float fcos(float x) {
    return __builtin_amdgcn_cosf(__builtin_amdgcn_fractf(x * 0.15915494309189535f));
}

__device__ __forceinline__ void glds16(const void* g, void* l) {
    __builtin_amdgcn_global_load_lds(
        (const __attribute__((address_space(1))) void*)g,
        (__attribute__((address_space(3))) void*)l, 16, 0, 0);
}

// XOR-swizzle for [R][32]bf16 LDS tiles read as 16-row x 16B-group fragments.
__device__ __forceinline__ int swzoff(int r, int sub) {
    return ((r << 2) | (sub ^ ((r >> 1) & 3))) << 4;   // byte offset
}

// whole-wave fp64 exact rescan of point nn; 4-way batched independent loads.
__device__ __forceinline__ int rescan64(const float* __restrict__ pts,
                                        const float4* __restrict__ kp4,
                                        int nn, int lane) {
    double pxd = (double)pts[nn*6+0], pyd = (double)pts[nn*6+1], pzd = (double)pts[nn*6+2];
    double ppd = pxd*pxd + pyd*pyd + pzd*pzd;
    double best = 1e300; int bbi = 0x7fffffff;
    for (int b = lane; b < 6912; b += 256) {
        int j0 = b, j1 = b + 64, j2 = b + 128, j3 = b + 192;
        float4 k0 = kp4[min(j0, V_N-1)];
        float4 k1 = kp4[min(j1, V_N-1)];
        float4 k2 = kp4[min(j2, V_N-1)];
        float4 k3 = kp4[min(j3, V_N-1)];
#define EVAL(kk, jj)                                                          \
        if (jj < V_N) {                                                       \
            double kx = (double)kk.x, ky = (double)kk.y, kz = (double)kk.z;   \
            double d = ppd - 2.0*(pxd*kx + pyd*ky + pzd*kz)                   \
                     + (kx*kx + ky*ky + kz*kz);                               \
            if (d < best || (d == best && jj < bbi)) { best = d; bbi = jj; }  \
        }
        EVAL(k0, j0); EVAL(k1, j1); EVAL(k2, j2); EVAL(k3, j3);
#undef EVAL
    }
#pragma unroll
    for (int off = 32; off >= 1; off >>= 1) {
        double od = __shfl_xor(best, off);
        int    oi = __shfl_xor(bbi, off);
        if (od < best || (od == best && oi < bbi)) { best = od; bbi = oi; }
    }
    return bbi;
}

// ---------------- merged: KNN scan (blocks 0..511, 4 pts/thread) + prep + wconv
#define SCAN_BLOCKS 512
#define PREP_BLOCKS 27
__global__ __launch_bounds__(256) void prep_scan_kernel(
    const float* __restrict__ pts, const float* __restrict__ keyp,
    const float* __restrict__ trans, const float* __restrict__ restp,
    const float* __restrict__ W1, const float* __restrict__ W2,
    const float* __restrict__ W3,
    float4* __restrict__ rinv4, float4* __restrict__ kp4, float4* __restrict__ rp4,
    unsigned short* __restrict__ wt1, unsigned short* __restrict__ wt2,
    unsigned short* __restrict__ wt3, float4* __restrict__ pb4)
{
    __shared__ float4 s_kp[CHUNK];   // 3.4 KB, scan blocks only
    int bx = blockIdx.x, tid = threadIdx.x;

    if (bx < SCAN_BLOCKS) {
        int g = bx & 15;             // point-group (1024 points)
        int c = bx >> 4;             // chunk
        int nA = g * 1024 + tid;
        int nB = nA + 256, nC = nA + 512, nD = nA + 768;
        int v0 = c * CHUNK;
        int nv = min(V_N - v0, CHUNK);
        if (tid < nv) {
            int v = v0 + tid;
            float kx = keyp[v*3+0], ky = keyp[v*3+1], kz = keyp[v*3+2];
            s_kp[tid] = make_float4(kx, ky, kz, kx*kx + ky*ky + kz*kz);
        }
        __syncthreads();

        float pxA = -2.0f*pts[nA*6+0], pyA = -2.0f*pts[nA*6+1], pzA = -2.0f*pts[nA*6+2];
        float pxB = -2.0f*pts[nB*6+0], pyB = -2.0f*pts[nB*6+1], pzB = -2.0f*pts[nB*6+2];
        float pxC = -2.0f*pts[nC*6+0], pyC = -2.0f*pts[nC*6+1], pzC = -2.0f*pts[nC*6+2];
        float pxD = -2.0f*pts[nD*6+0], pyD = -2.0f*pts[nD*6+1], pzD = -2.0f*pts[nD*6+2];
        float m1A = 1e30f, m2A = 1e30f; int biA = 0x7fffffff;
        float m1B = 1e30f, m2B = 1e30f; int biB = 0x7fffffff;
        float m1C = 1e30f, m2C = 1e30f; int biC = 0x7fffffff;
        float m1D = 1e30f, m2D = 1e30f; int biD = 0x7fffffff;

#define KP1(P, kk, jj)                                                      \
    {                                                                       \
        float d = __builtin_fmaf(px##P, kk.x,                               \
                  __builtin_fmaf(py##P, kk.y,                               \
                  __builtin_fmaf(pz##P, kk.z, kk.w)));                      \
        bool lt = d < m1##P;                                                \
        bi##P = lt ? (jj) : bi##P;                                          \
        m2##P = __builtin_amdgcn_fmed3f(m1##P, m2##P, d);                   \
        m1##P = fminf(m1##P, d);                                            \
    }
#define KNN_STEP(kk, jj)                                                    \
    { KP1(A, kk, jj) KP1(B, kk, jj) KP1(C, kk, jj) KP1(D, kk, jj) }

        int j = 0;
        for (; j + 8 <= nv; j += 8) {
            float4 k0 = s_kp[j],   k1 = s_kp[j+1], k2 = s_kp[j+2], k3 = s_kp[j+3];
            float4 k4 = s_kp[j+4], k5 = s_kp[j+5], k6 = s_kp[j+6], k7 = s_kp[j+7];
            KNN_STEP(k0, v0+j);   KNN_STEP(k1, v0+j+1);
            KNN_STEP(k2, v0+j+2); KNN_STEP(k3, v0+j+3);
            KNN_STEP(k4, v0+j+4); KNN_STEP(k5, v0+j+5);
            KNN_STEP(k6, v0+j+6); KNN_STEP(k7, v0+j+7);
        }
        for (; j < nv; ++j) {
            float4 k0 = s_kp[j];
            KNN_STEP(k0, v0+j);
        }
#undef KNN_STEP
#undef KP1
        pb4[(size_t)nA * NCHUNK + c] = make_float4(m1A, m2A, __int_as_float(biA), 0.0f);
        pb4[(size_t)nB * NCHUNK + c] = make_float4(m1B, m2B, __int_as_float(biB), 0.0f);
        pb4[(size_t)nC * NCHUNK + c] = make_float4(m1C, m2C, __int_as_float(biC), 0.0f);
        pb4[(size_t)nD * NCHUNK + c] = make_float4(m1D, m2D, __int_as_float(biD), 0.0f);

    } else if (bx < SCAN_BLOCKS + PREP_BLOCKS) {
        int v = (bx - SCAN_BLOCKS) * 256 + tid;
        if (v >= V_N) return;
        float m[16];
#pragma unroll
        for (int i = 0; i < 16; ++i) m[i] = trans[i * V_N + v];

        float i0  =  m[5]*m[10]*m[15] - m[5]*m[11]*m[14] - m[9]*m[6]*m[15] + m[9]*m[7]*m[14] + m[13]*m[6]*m[11] - m[13]*m[7]*m[10];
        float i4  = -m[4]*m[10]*m[15] + m[4]*m[11]*m[14] + m[8]*m[6]*m[15] - m[8]*m[7]*m[14] - m[12]*m[6]*m[11] + m[12]*m[7]*m[10];
        float i8  =  m[4]*m[9]*m[15]  - m[4]*m[11]*m[13] - m[8]*m[5]*m[15] + m[8]*m[7]*m[13] + m[12]*m[5]*m[11] - m[12]*m[7]*m[9];
        float i12 = -m[4]*m[9]*m[14]  + m[4]*m[10]*m[13] + m[8]*m[5]*m[14] - m[8]*m[6]*m[13] - m[12]*m[5]*m[10] + m[12]*m[6]*m[9];
        float i1  = -m[1]*m[10]*m[15] + m[1]*m[11]*m[14] + m[9]*m[2]*m[15] - m[9]*m[3]*m[14] - m[13]*m[2]*m[11] + m[13]*m[3]*m[10];
        float i5  =  m[0]*m[10]*m[15] - m[0]*m[11]*m[14] - m[8]*m[2]*m[15] + m[8]*m[3]*m[14] + m[12]*m[2]*m[11] - m[12]*m[3]*m[10];
        float i9  = -m[0]*m[9]*m[15]  + m[0]*m[11]*m[13] + m[8]*m[1]*m[15] - m[8]*m[3]*m[13] - m[12]*m[1]*m[11] + m[12]*m[3]*m[9];
        float i2  =  m[1]*m[6]*m[15]  - m[1]*m[7]*m[14]  - m[5]*m[2]*m[15] + m[5]*m[3]*m[14] + m[13]*m[2]*m[7]  - m[13]*m[3]*m[6];
        float i6  = -m[0]*m[6]*m[15]  + m[0]*m[7]*m[14]  + m[4]*m[2]*m[15] - m[4]*m[3]*m[14] - m[12]*m[2]*m[7]  + m[12]*m[3]*m[6];
        float i10 =  m[0]*m[5]*m[15]  - m[0]*m[7]*m[13]  - m[4]*m[1]*m[15] + m[4]*m[3]*m[13] + m[12]*m[1]*m[7]  - m[12]*m[3]*m[5];

        float det = m[0]*i0 + m[1]*i4 + m[2]*i8 + m[3]*i12;
        float id = 1.0f / det;
        rinv4[v*3+0] = make_float4(i0*id, i1*id, i2*id, i4*id);
        rinv4[v*3+1] = make_float4(i5*id, i6*id, i8*id, i9*id);
        rinv4[v*3+2] = make_float4(i10*id, 0.0f, 0.0f, 0.0f);

        float kx = keyp[v*3], ky = keyp[v*3+1], kz = keyp[v*3+2];
        kp4[v] = make_float4(kx, ky, kz, kx*kx + ky*ky + kz*kz);
        rp4[v] = make_float4(restp[v*3], restp[v*3+1], restp[v*3+2], 0.0f);
    } else {
        int idx = (bx - SCAN_BLOCKS - PREP_BLOCKS) * 256 + tid;
        const int N1 = 256 * D_INP;
        const int N2 = 256 * 256;
        if (idx < N1) {
            int n = idx / D_INP, k = idx - n * D_INP;
            float v = (k < D_IN) ? W1[k * 256 + n] : 0.0f;
            wt1[n * D_INP + k] = f2bf(v);
        } else if (idx < N1 + N2) {
            int t = idx - N1;
            int n = t >> 8, k = t & 255;
            wt2[n * 256 + k] = f2bf(W2[k * 256 + n]);
        } else if (idx < N1 + 2 * N2) {
            int t = idx - N1 - N2;
            int n = t >> 8, k = t & 255;
            wt3[n * 256 + k] = f2bf(W3[k * 256 + n]);
        }
    }
}

// ---------------- features v8 (R11-measured-best): 2 pts/wave ----------------
// Phase R: wave reads pb4[n0..n0+1][0..31] as ONE contiguous 1 KB coalesced
// fetch. Merge within each 32-lane half (5 shfl_xor), same lex (m1,bi) min +
// m2 certification; flagged points -> whole-wave fp64 rescan (batched loads).
// R12's 1-pt/wave variant was neutral-to-negative (doubled chain count +
// half-useful pb4 fetches offset the shorter chain) -- this is the optimum.
__global__ __launch_bounds__(256) void feat_kernel(
    const float* __restrict__ pts, const int* __restrict__ neigh,
    const float* __restrict__ latent, const float4* __restrict__ rinv4,
    const float4* __restrict__ kp4, const float4* __restrict__ rp4,
    const float4* __restrict__ pb4, unsigned short* __restrict__ X,
    float* __restrict__ out)
{
    __shared__ float s_vf[4][2][29];   // [wave][point][28+pad]
    __shared__ float s_dir[4][2][4];

    int t = threadIdx.x;
    int w = t >> 6, lane = t & 63;
    int n0 = blockIdx.x * 8 + w * 2;   // first point of this wave
    int ph = lane >> 5, g = lane & 31; // point-half, chunk (also Phase A's p/j)

    // hoisted pts loads (independent of pb4 merge)
    float pxA = pts[n0*6+0],     pyA = pts[n0*6+1],     pzA = pts[n0*6+2];
    float pxB = pts[(n0+1)*6+0], pyB = pts[(n0+1)*6+1], pzB = pts[(n0+1)*6+2];

    // ---- Phase R: coalesced load + within-half merge ----
    float4 P = pb4[(size_t)(n0 + ph) * NCHUNK + g];
    float m1 = P.x, m2 = P.y;
    int   bi = __float_as_int(P.z);
#pragma unroll
    for (int off = 1; off <= 16; off <<= 1) {     // xor stays within the half
        float o1 = __shfl_xor(m1, off);
        float o2 = __shfl_xor(m2, off);
        int   ob = __shfl_xor(bi, off);
        float nm2 = fminf(fminf(m2, o2), fmaxf(m1, o1));
        bool take = (o1 < m1) || (o1 == m1 && ob < bi);
        bi = take ? ob : bi;
        m1 = fminf(m1, o1);
        m2 = nm2;
    }
    // flags are half-uniform; broadcast via ballot, whole-wave rescans
    unsigned long long ambmask = __ballot(m2 - m1 < GAP_EPS);
    if (ambmask & 1ull) {
        int r = rescan64(pts, kp4, n0, lane);
        if (ph == 0) bi = r;
    }
    if (ambmask & (1ull << 32)) {
        int r = rescan64(pts, kp4, n0 + 1, lane);
        if (ph == 1) bi = r;
    }

    // ---- Phase A: batched gathers (2 points in parallel) ----
    int p = ph, j = g;
    int k8 = bi;                                   // half-uniform
    float px = p ? pxB : pxA, py = p ? pyB : pyA, pz = p ? pzB : pzA;

    int v7 = 0;
    if (j < 7) {
        v7 = neigh[k8*7 + j];
        float4 kq = kp4[v7];
        float4 rq = rp4[v7];
        float dx = px - kq.x, dy = py - kq.y, dz = pz - kq.z;
        s_vf[w][p][j*3+0] = rq.x;
        s_vf[w][p][j*3+1] = rq.y;
        s_vf[w][p][j*3+2] = rq.z;
        s_vf[w][p][21+j]  = sqrtf(dx*dx + dy*dy + dz*dz);
    } else if (j == 7) {
        float4 kq = kp4[k8];
        float ddx = px - kq.x, ddy = py - kq.y, ddz = pz - kq.z;
        float4 R0 = rinv4[k8*3+0];
        float4 R1 = rinv4[k8*3+1];
        float4 R2 = rinv4[k8*3+2];
        float d0 = R0.x*ddx + R0.y*ddy + R0.z*ddz;
        float d1 = R0.w*ddx + R1.x*ddy + R1.y*ddz;
        float d2 = R1.z*ddx + R1.w*ddy + R2.x*ddz;
        float nrm = fmaxf(sqrtf(d0*d0 + d1*d1 + d2*d2), 1e-12f);
        s_dir[w][p][0] = d0/nrm; s_dir[w][p][1] = d1/nrm; s_dir[w][p][2] = d2/nrm;
    }
    // no barrier: each wave reads only its own LDS rows (intra-wave lgkmcnt)

    // ---- Phase B: per-point posenc + stores ----
#pragma unroll
    for (int pp = 0; pp < 2; ++pp) {
        int n = n0 + pp;                                   // wave-uniform
        float dir0 = s_dir[w][pp][0];                      // LDS broadcasts
        float dir1 = s_dir[w][pp][1];
        float dir2 = s_dir[w][pp][2];

        // output tail (fp32): [dir(3), sin f-major (12), cos (12)]
        if (lane < 27) {
            float val;
            if (lane < 3) {
                val = (lane == 0) ? dir0 : (lane == 1) ? dir1 : dir2;
            } else {
                int tt = (lane < 15) ? lane - 3 : lane - 15;
                int m = tt % 3;
                float db = (m == 0) ? dir0 : (m == 1) ? dir1 : dir2;
                float a = db * (float)(1 << (tt/3));
                val = (lane < 15) ? fsin(a) : fcos(a);
            }
            out[(size_t)n*D_OUT + 256 + lane] = val;
        }

        // X row bf16, quad-per-lane; vf from wave-private LDS
#pragma unroll
        for (int it = 0; it < 3; ++it) {
            int base = it * 256 + (lane << 2);
            bool in_range = base < D_INP;
            int region = (base < 28) ? 0 : (base < 308) ? 1 : (base < 588) ? 2
                       : (base < 700) ? 3 : 4;

            int t0 = (region == 1) ? base - 28 : (region == 2) ? base - 308 : 0;
            int q = t0 / 28;
            int r = t0 - q * 28;
            float f0 = (float)(1 << q);
            float a[4];
#pragma unroll
            for (int jj = 0; jj < 4; ++jj) {
                int rj; float fj;
                if (region == 0) { rj = base + jj; fj = 1.0f; }
                else if (region <= 2) {
                    rj = r + jj; fj = f0;
                    if (rj >= 28) { rj -= 28; fj = f0 * 2.0f; }
                } else { rj = 0; fj = 0.0f; }
                a[jj] = s_vf[w][pp][rj] * fj;       // ds_read_b32
            }
            // latent neighbor index via full-exec shuffle (v7 at lanes pp*32+0..6)
            int idxc = (region == 3) ? (base - 588) >> 4 : 0;
            int vL = __shfl(v7, pp*32 + idxc);

            unsigned short r0, r1, r2, r3;
            if (region == 0) {
                r0 = f2bf(a[0]); r1 = f2bf(a[1]); r2 = f2bf(a[2]); r3 = f2bf(a[3]);
            } else if (region == 1) {
                r0 = f2bf(fsin(a[0])); r1 = f2bf(fsin(a[1]));
                r2 = f2bf(fsin(a[2])); r3 = f2bf(fsin(a[3]));
            } else if (region == 2) {
                r0 = f2bf(fcos(a[0])); r1 = f2bf(fcos(a[1]));
                r2 = f2bf(fcos(a[2])); r3 = f2bf(fcos(a[3]));
            } else if (region == 3) {
                int t3 = base - 588;
                float4 lv = *(const float4*)&latent[vL * 16 + (t3 & 15)];
                r0 = f2bf(lv.x); r1 = f2bf(lv.y); r2 = f2bf(lv.z); r3 = f2bf(lv.w);
            } else {
                r0 = r1 = r2 = r3 = 0;
            }
            if (in_range)
                *(ushort4*)&X[(size_t)n * D_INP + base] = make_ushort4(r0, r1, r2, r3);
        }
    }
}

// ---------------- fused 3-layer MLP: 32 rows/block, 2 blocks/CU --------------
#define HLD 264
__global__ __launch_bounds__(512) void mlp_kernel(
    const unsigned short* __restrict__ X,
    const unsigned short* __restrict__ wt1,
    const unsigned short* __restrict__ wt2,
    const unsigned short* __restrict__ wt3,
    const float* __restrict__ b1, const float* __restrict__ b2,
    const float* __restrict__ b3, float* __restrict__ out)
{
    __shared__ unsigned short As[2][32 * 32];     // 4 KB  (swizzled slots)
    __shared__ unsigned short Ws[2][256 * 32];    // 32 KB (swizzled slots)
    __shared__ unsigned short H1[32 * HLD];       // 16.9 KB
    __shared__ unsigned short H2[32 * HLD];       // 16.9 KB

    int t = threadIdx.x, l = t & 63, w = t >> 6;
    int bm = blockIdx.x * 32;
    int nbase = w * 32;
    int lrow = l & 15, lk = (l >> 4) * 8, sub = l >> 4;
    int col0 = l & 15, rquad = (l >> 4) * 4;

    f32x4 acc[2][2];
    short8 af[2], bf[2];

    auto stageA = [&](int buf, int k0) {
        if (t < 128) {
            int r = t >> 2, sg = (t & 3) ^ ((r >> 1) & 3);
            glds16(X + (size_t)(bm + r) * D_INP + k0 + sg * 8,
                   (char*)As[buf] + t * 16);
        }
    };
    auto stageW = [&](int buf, const unsigned short* wsrc, int ld, int k0) {
#pragma unroll
        for (int i = 0; i < 2; ++i) {
            int c = i * 512 + t;
            int r = c >> 2, sg = (c & 3) ^ ((r >> 1) & 3);
            glds16(wsrc + (size_t)r * ld + k0 + sg * 8,
                   (char*)Ws[buf] + (size_t)c * 16);
        }
    };

    // ---- layer 1: X[704] @ wt1^T -> relu -> H1 ----
#pragma unroll
    for (int mi = 0; mi < 2; ++mi)
#pragma unroll
        for (int ni = 0; ni < 2; ++ni) acc[mi][ni] = {0.f, 0.f, 0.f, 0.f};

    stageA(0, 0);
    stageW(0, wt1, D_INP, 0);
    __syncthreads();
    const int NK1 = D_INP / 32;                      // 22
    for (int ks = 0; ks < NK1; ++ks) {
        int cur = ks & 1;
        if (ks + 1 < NK1) {
            stageA(cur ^ 1, (ks + 1) * 32);
            stageW(cur ^ 1, wt1, D_INP, (ks + 1) * 32);
        }
#pragma unroll
        for (int mi = 0; mi < 2; ++mi)
            af[mi] = *(const short8*)((const char*)As[cur] + swzoff(mi*16 + lrow, sub));
#pragma unroll
        for (int ni = 0; ni < 2; ++ni)
            bf[ni] = *(const short8*)((const char*)Ws[cur] + swzoff(nbase + ni*16 + lrow, sub));
#pragma unroll
        for (int mi = 0; mi < 2; ++mi)
#pragma unroll
            for (int ni = 0; ni < 2; ++ni)
                acc[mi][ni] = __builtin_amdgcn_mfma_f32_16x16x32_bf16(
                    af[mi], bf[ni], acc[mi][ni], 0, 0, 0);
        __syncthreads();
    }
    stageW(0, wt2, D_HID, 0);   // prefetch layer-2 under epilogue
#pragma unroll
    for (int mi = 0; mi < 2; ++mi)
#pragma unroll
        for (int ni = 0; ni < 2; ++ni) {
            int col = nbase + ni * 16 + col0;
            float bv = b1[col];
#pragma unroll
            for (int r = 0; r < 4; ++r) {
                int row = mi * 16 + rquad + r;
                H1[row * HLD + col] = f2bf(fmaxf(acc[mi][ni][r] + bv, 0.0f));
            }
        }
    __syncthreads();

    // ---- layer 2: H1 @ wt2^T -> relu -> H2 ----
#pragma unroll
    for (int mi = 0; mi < 2; ++mi)
#pragma unroll
        for (int ni = 0; ni < 2; ++ni) acc[mi][ni] = {0.f, 0.f, 0.f, 0.f};

    const int NK2 = D_HID / 32;                      // 8
    for (int ks = 0; ks < NK2; ++ks) {
        int cur = ks & 1;
        if (ks + 1 < NK2) stageW(cur ^ 1, wt2, D_HID, (ks + 1) * 32);
#pragma unroll
        for (int mi = 0; mi < 2; ++mi)
            af[mi] = *(const short8*)&H1[(mi * 16 + lrow) * HLD + ks * 32 + lk];
#pragma unroll
        for (int ni = 0; ni < 2; ++ni)
            bf[ni] = *(const short8*)((const char*)Ws[cur] + swzoff(nbase + ni*16 + lrow, sub));
#pragma unroll
        for (int mi = 0; mi < 2; ++mi)
#pragma unroll
            for (int ni = 0; ni < 2; ++ni)
                acc[mi][ni] = __builtin_amdgcn_mfma_f32_16x16x32_bf16(
                    af[mi], bf[ni], acc[mi][ni], 0, 0, 0);
        __syncthreads();
    }
    stageW(0, wt3, D_HID, 0);   // prefetch layer-3 under epilogue
#pragma unroll
    for (int mi = 0; mi < 2; ++mi)
#pragma unroll
        for (int ni = 0; ni < 2; ++ni) {
            int col = nbase + ni * 16 + col0;
            float bv = b2[col];
#pragma unroll
            for (int r = 0; r < 4; ++r) {
                int row = mi * 16 + rquad + r;
                H2[row * HLD + col] = f2bf(fmaxf(acc[mi][ni][r] + bv, 0.0f));
            }
        }
    __syncthreads();

    // ---- layer 3: H2 @ wt3^T + b3 -> out (fp32) ----
#pragma unroll
    for (int mi = 0; mi < 2; ++mi)
#pragma unroll
        for (int ni = 0; ni < 2; ++ni) acc[mi][ni] = {0.f, 0.f, 0.f, 0.f};

    for (int ks = 0; ks < NK2; ++ks) {
        int cur = ks & 1;
        if (ks + 1 < NK2) stageW(cur ^ 1, wt3, D_HID, (ks + 1) * 32);
#pragma unroll
        for (int mi = 0; mi < 2; ++mi)
            af[mi] = *(const short8*)&H2[(mi * 16 + lrow) * HLD + ks * 32 + lk];
#pragma unroll
        for (int ni = 0; ni < 2; ++ni)
            bf[ni] = *(const short8*)((const char*)Ws[cur] + swzoff(nbase + ni*16 + lrow, sub));
#pragma unroll
        for (int mi = 0; mi < 2; ++mi)
#pragma unroll
            for (int ni = 0; ni < 2; ++ni)
                acc[mi][ni] = __builtin_amdgcn_mfma_f32_16x16x32_bf16(
                    af[mi], bf[ni], acc[mi][ni], 0, 0, 0);
        __syncthreads();
    }
#pragma unroll
    for (int mi = 0; mi < 2; ++mi)
#pragma unroll
        for (int ni = 0; ni < 2; ++ni) {
            int col = nbase + ni * 16 + col0;
            float bv = b3[col];
#pragma unroll
            for (int r = 0; r < 4; ++r) {
                int row = bm + mi * 16 + rquad + r;
                out[(size_t)row * D_OUT + col] = acc[mi][ni][r] + bv;
            }
        }
}

extern "C" void kernel_launch(void* const* d_in, const int* in_sizes, int n_in,
                              void* d_out, int out_size, void* d_ws, size_t ws_size,
                              hipStream_t stream) {
    const float* pts    = (const float*)d_in[0];
    const float* keyp   = (const float*)d_in[1];
    const float* trans  = (const float*)d_in[2];
    const int*   neigh  = (const int*)d_in[3];
    const float* restp  = (const float*)d_in[4];
    const float* latent = (const float*)d_in[5];
    const float* W1     = (const float*)d_in[6];
    const float* b1     = (const float*)d_in[7];
    const float* W2     = (const float*)d_in[8];
    const float* b2     = (const float*)d_in[9];
    const float* W3     = (const float*)d_in[10];
    const float* b3     = (const float*)d_in[11];
    float* out = (float*)d_out;

    float* wsf = (float*)d_ws;
    float4*         rinv4 = (float4*)(wsf + RINV4_OFF);
    float4*         kp4   = (float4*)(wsf + KP4_OFF);
    float4*         rp4   = (float4*)(wsf + RP4_OFF);
    float4*         pb4   = (float4*)(wsf + PB4_OFF);
    unsigned short* wt1   = (unsigned short*)(wsf + WT1_OFF);
    unsigned short* wt2   = (unsigned short*)(wsf + WT2_OFF);
    unsigned short* wt3   = (unsigned short*)(wsf + WT3_OFF);
    unsigned short* X     = (unsigned short*)(wsf + X_OFF);

    int wconv_blocks = (256*D_INP + 2*256*256 + 255) / 256;
    prep_scan_kernel<<<SCAN_BLOCKS + PREP_BLOCKS + wconv_blocks, 256, 0, stream>>>(
        pts, keyp, trans, restp, W1, W2, W3, rinv4, kp4, rp4, wt1, wt2, wt3, pb4);
    feat_kernel<<<N_PTS/8, 256, 0, stream>>>(pts, neigh, latent, rinv4,
                                             kp4, rp4, pb4, X, out);
    mlp_kernel<<<N_PTS/32, 512, 0, stream>>>(X, wt1, wt2, wt3, b1, b2, b3, out);
}